// Round 2
// baseline (197.698 us; speedup 1.0000x reference)
//
#include <hip/hip_runtime.h>
#include <hip/hip_bf16.h>

#define NB 8
#define NPTS 20000
#define DD 128
#define MM 1024
#define INV_T (1.0f/0.07f)
#define NTILES (NB*8*8)   // 512 tile-blocks

typedef __attribute__((ext_vector_type(8))) short bf16x8;
typedef __attribute__((ext_vector_type(4))) float f32x4;

// K1: gather + L2-normalize + bf16 cast; also zero colsum + completion counter.
// 4 waves/block, one gathered row per wave.
__global__ __launch_bounds__(256) void gather_norm(
    const float* __restrict__ feats0, const float* __restrict__ feats1,
    const int* __restrict__ corrs,   // int32 words; may actually be int64 pairs
    __hip_bfloat16* __restrict__ f0s, __hip_bfloat16* __restrict__ f1s,
    float* __restrict__ colsum, unsigned int* __restrict__ cnt)
{
    int tid  = threadIdx.x;
    int lane = tid & 63;
    int wv   = tid >> 6;
    int rid  = blockIdx.x * 4 + wv;      // [0, 2*NB*MM)

    // zero colsum (8192 floats) + counter; kernel boundary orders this vs K2
    if (blockIdx.x < 32) colsum[blockIdx.x * 256 + tid] = 0.0f;
    if (blockIdx.x == 32 && tid == 0) *cnt = 0u;

    // Detect corrs dtype: int64 data has zero hi-words in the first 32 values.
    int probe = (lane < 32) ? corrs[2*lane + 1] : 0;
    bool is64 = (__ballot(probe != 0) == 0ULL);

    int t  = rid >> 13;                  // 0 -> feats0 side, 1 -> feats1 side
    int bm = rid & (NB*MM - 1);
    int b  = bm >> 10;
    int m  = bm & (MM - 1);

    int widx = b*(MM*2) + m*2 + t;       // corrs[b, m, t]
    int idx  = is64 ? corrs[widx*2] : corrs[widx];

    const float* src = (t == 0 ? feats0 : feats1) + ((size_t)b * NPTS + (size_t)idx) * DD;
    __hip_bfloat16* dst = (t == 0 ? f0s : f1s) + (size_t)bm * DD;

    float2 v = ((const float2*)src)[lane];
    float ss = v.x*v.x + v.y*v.y;
    #pragma unroll
    for (int off = 32; off >= 1; off >>= 1) ss += __shfl_xor(ss, off);
    float s = 1.0f / fmaxf(sqrtf(ss), 1e-12f);

    __hip_bfloat162 h;
    h.x = __float2bfloat16(v.x * s);
    h.y = __float2bfloat16(v.y * s);
    ((__hip_bfloat162*)dst)[lane] = h;
}

// K2: per (b, ti, tj) 128x128 logits tile via MFMA bf16 + exp-colsum atomics +
// diag stores, with fused last-block loss finalization.
__global__ __launch_bounds__(256) void logits_fused(
    const short* __restrict__ f1s, const short* __restrict__ f0s,
    float* __restrict__ colsum, float* __restrict__ diag,
    unsigned int* __restrict__ cnt, float* __restrict__ out)
{
    int tj = blockIdx.x, ti = blockIdx.y, b = blockIdx.z;
    int tid  = threadIdx.x;
    int w    = tid >> 6;
    int lane = tid & 63;
    int n16  = lane & 15;
    int quad = lane >> 4;

    const short* Abase = f1s + (size_t)(b*MM + ti*128 + w*32 + n16) * DD;
    const short* Bbase = f0s + (size_t)(b*MM + tj*128 + n16) * DD;

    f32x4 acc[2][8];
    #pragma unroll
    for (int fr = 0; fr < 2; fr++)
        #pragma unroll
        for (int fc = 0; fc < 8; fc++)
            acc[fr][fc] = {0.f, 0.f, 0.f, 0.f};

    #pragma unroll
    for (int ks = 0; ks < 4; ks++) {
        int koff = ks*32 + quad*8;
        bf16x8 a[2], bb[8];
        #pragma unroll
        for (int fr = 0; fr < 2; fr++)
            a[fr] = *(const bf16x8*)(Abase + fr*16*DD + koff);
        #pragma unroll
        for (int fc = 0; fc < 8; fc++)
            bb[fc] = *(const bf16x8*)(Bbase + fc*16*DD + koff);
        #pragma unroll
        for (int fr = 0; fr < 2; fr++)
            #pragma unroll
            for (int fc = 0; fc < 8; fc++)
                acc[fr][fc] = __builtin_amdgcn_mfma_f32_16x16x32_bf16(
                    a[fr], bb[fc], acc[fr][fc], 0, 0, 0);
    }

    __shared__ float lcol[128];
    if (tid < 128) lcol[tid] = 0.f;
    __syncthreads();

    bool diagblk = (ti == tj);
    #pragma unroll
    for (int fc = 0; fc < 8; fc++) {
        float s = 0.f;
        #pragma unroll
        for (int fr = 0; fr < 2; fr++) {
            #pragma unroll
            for (int r = 0; r < 4; r++) {
                // C/D layout: col = lane&15, row = quad*4 + r
                float logit = acc[fr][fc][r] * INV_T;
                int rl = w*32 + fr*16 + quad*4 + r;
                int cl = fc*16 + n16;
                if (diagblk && rl == cl)
                    diag[b*MM + ti*128 + rl] = logit;
                s += __expf(logit);
            }
        }
        s += __shfl_xor(s, 16);
        s += __shfl_xor(s, 32);
        if (quad == 0) atomicAdd(&lcol[fc*16 + n16], s);
    }
    __syncthreads();
    if (tid < 128) atomicAdd(&colsum[b*MM + tj*128 + tid], lcol[tid]);

    // --- fused finalize: last block computes the loss ---
    __threadfence();            // release: diag stores + colsum atomics visible
    __syncthreads();            // all threads of this block have fenced
    __shared__ unsigned int lastflag;
    if (tid == 0) lastflag = atomicAdd(cnt, 1u);
    __syncthreads();
    if (lastflag == NTILES - 1) {
        __threadfence();        // acquire side
        float accl = 0.f;
        for (int k = tid; k < NB*MM; k += 256) {
            float cs = __hip_atomic_load(&colsum[k], __ATOMIC_RELAXED,
                                         __HIP_MEMORY_SCOPE_AGENT);
            float dg = __hip_atomic_load(&diag[k], __ATOMIC_RELAXED,
                                         __HIP_MEMORY_SCOPE_AGENT);
            accl += dg - __logf(cs);
        }
        #pragma unroll
        for (int off = 32; off >= 1; off >>= 1) accl += __shfl_xor(accl, off);
        __shared__ float wsum[4];
        if (lane == 0) wsum[w] = accl;
        __syncthreads();
        if (tid == 0)
            out[0] = -(wsum[0] + wsum[1] + wsum[2] + wsum[3]) * (1.0f / (NB*MM));
    }
}

extern "C" void kernel_launch(void* const* d_in, const int* in_sizes, int n_in,
                              void* d_out, int out_size, void* d_ws, size_t ws_size,
                              hipStream_t stream)
{
    const float* feats0 = (const float*)d_in[0];
    const float* feats1 = (const float*)d_in[1];
    const int*   corrs  = (const int*)d_in[2];

    char* ws = (char*)d_ws;
    __hip_bfloat16* f0s = (__hip_bfloat16*)ws;                              // 2 MB
    __hip_bfloat16* f1s = (__hip_bfloat16*)(ws + (size_t)NB*MM*DD*2);       // 2 MB
    float* colsum = (float*)(ws + 2*(size_t)NB*MM*DD*2);                    // 32 KB
    float* diag   = colsum + NB*MM;                                         // 32 KB
    unsigned int* cnt = (unsigned int*)(diag + NB*MM);                      // 4 B

    gather_norm<<<(2*NB*MM)/4, 256, 0, stream>>>(feats0, feats1, corrs,
                                                 f0s, f1s, colsum, cnt);
    logits_fused<<<dim3(8, 8, NB), 256, 0, stream>>>((const short*)f1s,
                                                     (const short*)f0s,
                                                     colsum, diag, cnt,
                                                     (float*)d_out);
}

// Round 3
// 169.027 us; speedup vs baseline: 1.1696x; 1.1696x over previous
//
#include <hip/hip_runtime.h>
#include <hip/hip_bf16.h>

#define NB 8
#define NPTS 20000
#define DD 128
#define MM 1024
#define INV_T (1.0f/0.07f)

typedef __attribute__((ext_vector_type(8))) short bf16x8;
typedef __attribute__((ext_vector_type(4))) float f32x4;

// K1: gather + L2-normalize + bf16 cast; also zero colsum.
// 4 waves/block, one gathered row per wave. NO fences anywhere — kernel
// boundaries provide all ordering (agent-scope fences = L2 flush on gfx950,
// measured 55us regression in R2).
__global__ __launch_bounds__(256) void gather_norm(
    const float* __restrict__ feats0, const float* __restrict__ feats1,
    const int* __restrict__ corrs,   // int32 words; may actually be int64 pairs
    __hip_bfloat16* __restrict__ f0s, __hip_bfloat16* __restrict__ f1s,
    float* __restrict__ colsum)
{
    int tid  = threadIdx.x;
    int lane = tid & 63;
    int wv   = tid >> 6;
    int rid  = blockIdx.x * 4 + wv;      // [0, 2*NB*MM)

    // zero colsum (8192 floats); kernel boundary orders this vs K2
    if (blockIdx.x < 32) colsum[blockIdx.x * 256 + tid] = 0.0f;

    // Detect corrs dtype: int64 data has zero hi-words in the first 32 values.
    int probe = (lane < 32) ? corrs[2*lane + 1] : 0;
    bool is64 = (__ballot(probe != 0) == 0ULL);

    int t  = rid >> 13;                  // 0 -> feats0 side, 1 -> feats1 side
    int bm = rid & (NB*MM - 1);
    int b  = bm >> 10;
    int m  = bm & (MM - 1);

    int widx = b*(MM*2) + m*2 + t;       // corrs[b, m, t]
    int idx  = is64 ? corrs[widx*2] : corrs[widx];

    const float* src = (t == 0 ? feats0 : feats1) + ((size_t)b * NPTS + (size_t)idx) * DD;
    __hip_bfloat16* dst = (t == 0 ? f0s : f1s) + (size_t)bm * DD;

    float2 v = ((const float2*)src)[lane];
    float ss = v.x*v.x + v.y*v.y;
    #pragma unroll
    for (int off = 32; off >= 1; off >>= 1) ss += __shfl_xor(ss, off);
    float s = 1.0f / fmaxf(sqrtf(ss), 1e-12f);

    __hip_bfloat162 h;
    h.x = __float2bfloat16(v.x * s);
    h.y = __float2bfloat16(v.y * s);
    ((__hip_bfloat162*)dst)[lane] = h;
}

// K2: per (b, ti, tj) 128x128 logits tile via MFMA bf16. Epilogue: exp +
// per-column partial sums -> global atomicAdd (device-scope, no fence
// needed); diagonal lanes write diag[b,j].
__global__ __launch_bounds__(256) void logits_lse(
    const short* __restrict__ f1s, const short* __restrict__ f0s,
    float* __restrict__ colsum, float* __restrict__ diag)
{
    int tj = blockIdx.x, ti = blockIdx.y, b = blockIdx.z;
    int tid  = threadIdx.x;
    int w    = tid >> 6;
    int lane = tid & 63;
    int n16  = lane & 15;
    int quad = lane >> 4;

    const short* Abase = f1s + (size_t)(b*MM + ti*128 + w*32 + n16) * DD;
    const short* Bbase = f0s + (size_t)(b*MM + tj*128 + n16) * DD;

    f32x4 acc[2][8];
    #pragma unroll
    for (int fr = 0; fr < 2; fr++)
        #pragma unroll
        for (int fc = 0; fc < 8; fc++)
            acc[fr][fc] = {0.f, 0.f, 0.f, 0.f};

    #pragma unroll
    for (int ks = 0; ks < 4; ks++) {
        int koff = ks*32 + quad*8;
        bf16x8 a[2], bb[8];
        #pragma unroll
        for (int fr = 0; fr < 2; fr++)
            a[fr] = *(const bf16x8*)(Abase + fr*16*DD + koff);
        #pragma unroll
        for (int fc = 0; fc < 8; fc++)
            bb[fc] = *(const bf16x8*)(Bbase + fc*16*DD + koff);
        #pragma unroll
        for (int fr = 0; fr < 2; fr++)
            #pragma unroll
            for (int fc = 0; fc < 8; fc++)
                acc[fr][fc] = __builtin_amdgcn_mfma_f32_16x16x32_bf16(
                    a[fr], bb[fc], acc[fr][fc], 0, 0, 0);
    }

    __shared__ float lcol[128];
    if (tid < 128) lcol[tid] = 0.f;
    __syncthreads();

    bool diagblk = (ti == tj);
    #pragma unroll
    for (int fc = 0; fc < 8; fc++) {
        float s = 0.f;
        #pragma unroll
        for (int fr = 0; fr < 2; fr++) {
            #pragma unroll
            for (int r = 0; r < 4; r++) {
                // C/D layout: col = lane&15, row = quad*4 + r
                float logit = acc[fr][fc][r] * INV_T;
                int rl = w*32 + fr*16 + quad*4 + r;
                int cl = fc*16 + n16;
                if (diagblk && rl == cl)
                    diag[b*MM + ti*128 + rl] = logit;
                s += __expf(logit);
            }
        }
        s += __shfl_xor(s, 16);
        s += __shfl_xor(s, 32);
        if (quad == 0) atomicAdd(&lcol[fc*16 + n16], s);
    }
    __syncthreads();
    if (tid < 128) atomicAdd(&colsum[b*MM + tj*128 + tid], lcol[tid]);
}

// K3: loss = -mean(diag - log(colsum)) over 8192 entries.
__global__ __launch_bounds__(256) void finalize(
    const float* __restrict__ colsum, const float* __restrict__ diag,
    float* __restrict__ out)
{
    int tid = threadIdx.x;
    float acc = 0.f;
    for (int k = tid; k < NB*MM; k += 256)
        acc += diag[k] - __logf(colsum[k]);
    #pragma unroll
    for (int off = 32; off >= 1; off >>= 1) acc += __shfl_xor(acc, off);
    __shared__ float wsum[4];
    if ((tid & 63) == 0) wsum[tid >> 6] = acc;
    __syncthreads();
    if (tid == 0) out[0] = -(wsum[0] + wsum[1] + wsum[2] + wsum[3]) * (1.0f / (NB*MM));
}

extern "C" void kernel_launch(void* const* d_in, const int* in_sizes, int n_in,
                              void* d_out, int out_size, void* d_ws, size_t ws_size,
                              hipStream_t stream)
{
    const float* feats0 = (const float*)d_in[0];
    const float* feats1 = (const float*)d_in[1];
    const int*   corrs  = (const int*)d_in[2];

    char* ws = (char*)d_ws;
    __hip_bfloat16* f0s = (__hip_bfloat16*)ws;                              // 2 MB
    __hip_bfloat16* f1s = (__hip_bfloat16*)(ws + (size_t)NB*MM*DD*2);       // 2 MB
    float* colsum = (float*)(ws + 2*(size_t)NB*MM*DD*2);                    // 32 KB
    float* diag   = colsum + NB*MM;                                         // 32 KB

    gather_norm<<<(2*NB*MM)/4, 256, 0, stream>>>(feats0, feats1, corrs,
                                                 f0s, f1s, colsum);
    logits_lse<<<dim3(8, 8, NB), 256, 0, stream>>>((const short*)f1s,
                                                   (const short*)f0s,
                                                   colsum, diag);
    finalize<<<1, 256, 0, stream>>>(colsum, diag, (float*)d_out);
}